// Round 14
// baseline (170.679 us; speedup 1.0000x reference)
//
#include <hip/hip_runtime.h>

#define N_NODES 100000
#define IN_CH 128
#define HID_CH 256
#define OUT_CH 128
#define N_EDGES 1600000

#define NBK 782                                   // ceil(N_NODES/128) buckets of 128 nodes
#define BIN_BLOCKS 256
#define EPB (N_EDGES / BIN_BLOCKS)                // 6250 edges per bin block
#define BKT_CAP 4096                              // fixed bucket region (mean 2046, z~45)

typedef __attribute__((ext_vector_type(8))) short short8;
typedef __attribute__((ext_vector_type(4))) float f32x4;

// bf16 <-> f32 helpers (bit ops; finite data only)
__device__ __forceinline__ float b2f(ushort u) {
    unsigned int x = ((unsigned int)u) << 16;
    return __uint_as_float(x);
}
__device__ __forceinline__ ushort f2b(float f) {
    unsigned int u = __float_as_uint(f);
    u += 0x7FFFu + ((u >> 16) & 1u);   // round-to-nearest-even
    return (ushort)(u >> 16);
}

// ---------------------------------------------------------------------------
// Prep (+ fused ghist): x fp32 -> xb bf16 ; W1 -> W1T ; W2 -> W2T ;
// last 256 blocks: per-(block,bucket) dst histogram (transposed store).
// ---------------------------------------------------------------------------
#define PREP_X_BLOCKS 6250
#define PREP_W1_BLOCKS 128
#define PREP_W2_BLOCKS 128
#define PREP_TOTAL (PREP_X_BLOCKS + PREP_W1_BLOCKS + PREP_W2_BLOCKS)
__global__ __launch_bounds__(256) void prep_kernel(
    const float* __restrict__ x, const float* __restrict__ W1,
    const float* __restrict__ W2, const int* __restrict__ dst,
    ushort* __restrict__ xb, ushort* __restrict__ W1T,
    ushort* __restrict__ W2T, int* __restrict__ histT) {
    const int b = blockIdx.x;
    const int t = threadIdx.x;
    if (b < PREP_X_BLOCKS) {
        const size_t i = (size_t)b * 2048 + t * 8;
        float4 a = *reinterpret_cast<const float4*>(x + i);
        float4 c = *reinterpret_cast<const float4*>(x + i + 4);
        ushort v[8] = {f2b(a.x), f2b(a.y), f2b(a.z), f2b(a.w),
                       f2b(c.x), f2b(c.y), f2b(c.z), f2b(c.w)};
        *reinterpret_cast<short8*>(xb + i) = *reinterpret_cast<short8*>(v);
    } else if (b < PREP_X_BLOCKS + PREP_W1_BLOCKS) {
        const int i = (b - PREP_X_BLOCKS) * 256 + t;     // oc*128 + k
        const int oc = i >> 7, k = i & 127;
        W1T[i] = f2b(W1[k * HID_CH + oc]);
    } else if (b < PREP_TOTAL) {
        const int i = (b - PREP_X_BLOCKS - PREP_W1_BLOCKS) * 256 + t; // oc*256+k
        const int oc = i >> 8, k = i & 255;
        W2T[i] = f2b(W2[k * OUT_CH + oc]);
    } else {
        __shared__ int h[NBK];
        const int bb = b - PREP_TOTAL;
        for (int k = t; k < NBK; k += 256) h[k] = 0;
        __syncthreads();
        const int base = bb * EPB;
        for (int i = t; i < EPB; i += 256)
            atomicAdd(&h[dst[base + i] >> 7], 1);
        __syncthreads();
        for (int k = t; k < NBK; k += 256) histT[k * BIN_BLOCKS + bb] = h[k];
    }
}

// ---------------------------------------------------------------------------
// Per-bucket exclusive scan over the 256 block counts (bucket regions fixed).
// ---------------------------------------------------------------------------
__global__ __launch_bounds__(256) void scanA_kernel(
    const int* __restrict__ histT, int* __restrict__ blockBaseP,
    int* __restrict__ bktTotal) {
    __shared__ int ts[256];
    const int bk = blockIdx.x, t = threadIdx.x;
    const int v = histT[bk * BIN_BLOCKS + t];
    ts[t] = v;
    __syncthreads();
    #pragma unroll
    for (int o = 1; o < 256; o <<= 1) {
        int add = (t >= o) ? ts[t - o] : 0;
        __syncthreads();
        ts[t] += add;
        __syncthreads();
    }
    blockBaseP[bk * BIN_BLOCKS + t] = ts[t] - v;
    if (t == 255) bktTotal[bk] = ts[255];
}

// ---------------------------------------------------------------------------
// bin: LDS-sort the block's EPB edges by bucket, then flush each bucket-run
// CONTIGUOUSLY into its (block,bucket) slot -> line-friendly writes (~15 MB
// total vs ~102 MB for random 4 B scatter). Content per region unchanged.
// ---------------------------------------------------------------------------
__global__ __launch_bounds__(256) void bin_kernel(
    const int* __restrict__ src, const int* __restrict__ dst,
    const int* __restrict__ blockBaseP,
    unsigned int* __restrict__ ebuf) {
    __shared__ unsigned int srt[EPB];     // 25 KB sorted entries
    __shared__ int h[NBK];                // counts -> local exclusive base
    __shared__ int cur[NBK];
    __shared__ int part[256];
    const int b = blockIdx.x, t = threadIdx.x;
    for (int k = t; k < NBK; k += 256) h[k] = 0;
    __syncthreads();
    const int ebase = b * EPB;
    for (int i = t; i < EPB; i += 256)
        atomicAdd(&h[dst[ebase + i] >> 7], 1);
    __syncthreads();
    // chunked exclusive scan: thread t owns bins 4t..4t+3
    const int k0 = t * 4;
    const int s0 = (k0 + 0 < NBK) ? h[k0 + 0] : 0;
    const int s1 = (k0 + 1 < NBK) ? h[k0 + 1] : 0;
    const int s2 = (k0 + 2 < NBK) ? h[k0 + 2] : 0;
    const int s3 = (k0 + 3 < NBK) ? h[k0 + 3] : 0;
    const int tot = s0 + s1 + s2 + s3;
    part[t] = tot;
    __syncthreads();
    #pragma unroll
    for (int o = 1; o < 256; o <<= 1) {
        int add = (t >= o) ? part[t - o] : 0;
        __syncthreads();
        part[t] += add;
        __syncthreads();
    }
    const int excl = part[t] - tot;
    if (k0 + 0 < NBK) { h[k0 + 0] = excl;               cur[k0 + 0] = excl; }
    if (k0 + 1 < NBK) { h[k0 + 1] = excl + s0;          cur[k0 + 1] = excl + s0; }
    if (k0 + 2 < NBK) { h[k0 + 2] = excl + s0 + s1;     cur[k0 + 2] = excl + s0 + s1; }
    if (k0 + 3 < NBK) { h[k0 + 3] = excl + s0 + s1 + s2; cur[k0 + 3] = excl + s0 + s1 + s2; }
    __syncthreads();
    // scatter into LDS sorted order (stable w.r.t. atomic rank)
    for (int i = t; i < EPB; i += 256) {
        const int d = dst[ebase + i];
        const int s = src[ebase + i];
        const int bk = d >> 7;
        const int p = atomicAdd(&cur[bk], 1);
        srt[p] = ((unsigned int)(d & 127) << 17) | (unsigned int)s;
    }
    __syncthreads();
    // flush runs: thread t flushes its 4 bins contiguously
    #pragma unroll
    for (int j = 0; j < 4; ++j) {
        const int k = k0 + j;
        if (k < NBK) {
            const int lb = h[k];
            const int le = cur[k];
            unsigned int* gp = ebuf + (size_t)k * BKT_CAP
                             + blockBaseP[k * BIN_BLOCKS + b];
            for (int p = lb; p < le; ++p) gp[p - lb] = srt[p];
        }
    }
}

// ---------------------------------------------------------------------------
// group: node-sort each bucket in LDS, stream csr_src out COALESCED.
// Writes per-node beg/end.
// ---------------------------------------------------------------------------
__global__ __launch_bounds__(256) void group_kernel(
    const unsigned int* __restrict__ ebuf,
    const int* __restrict__ bktTotal,
    int* __restrict__ csr_src, int* __restrict__ begA, int* __restrict__ endA) {
    __shared__ unsigned int ein[BKT_CAP];   // 16 KB
    __shared__ int srt[BKT_CAP];            // 16 KB
    __shared__ int hist[128];
    __shared__ int cur[128];
    const int bk = blockIdx.x, t = threadIdx.x;
    if (t < 128) hist[t] = 0;
    __syncthreads();
    const int start = bk * BKT_CAP;
    const int cnt = min(bktTotal[bk], BKT_CAP);
    for (int i = t; i < cnt; i += 256) {
        const unsigned int e = ebuf[start + i];
        ein[i] = e;
        atomicAdd(&hist[e >> 17], 1);
    }
    __syncthreads();
    int v = (t < 128) ? hist[t] : 0;
    #pragma unroll
    for (int o = 1; o < 128; o <<= 1) {
        int add = (t < 128 && t >= o) ? hist[t - o] : 0;
        __syncthreads();
        if (t < 128) hist[t] += add;
        __syncthreads();
    }
    if (t < 128) {
        const int excl = hist[t] - v;
        cur[t] = excl;
        const int node = bk * 128 + t;
        if (node < N_NODES) {
            begA[node] = start + excl;
            endA[node] = start + hist[t];   // inclusive scan = end
        }
    }
    __syncthreads();
    for (int i = t; i < cnt; i += 256) {
        const unsigned int e = ein[i];
        const int dl = e >> 17;
        const int p = atomicAdd(&cur[dl], 1);
        srt[p] = (int)(e & 0x1FFFF);
    }
    __syncthreads();
    for (int i = t; i < cnt; i += 256)
        csr_src[start + i] = srt[i];        // fully coalesced
}

// ---------------------------------------------------------------------------
// Gather-aggregate fused with GIN self-term (bf16 rows, fp32 accum):
//   h_in[i] = bf16( (1+eps)*x[i] + sum_{j in N(i)} x[j] )
// 8 nodes/block, 32 threads/node, ushort4 per thread; 32-edge tiles with
// EIGHT independent accumulator chains via shfl (8 row loads in flight).
// ---------------------------------------------------------------------------
__global__ __launch_bounds__(256) void gather_kernel(
    const ushort* __restrict__ xb,
    const float* __restrict__ eps_p,
    const int* __restrict__ begA,
    const int* __restrict__ endA,
    const int* __restrict__ csr_src,
    ushort* __restrict__ h_in) {
    const int node = blockIdx.x * 8 + (threadIdx.x >> 5);
    const int l32 = threadIdx.x & 31;
    const int c = l32 * 4;
    const int beg = begA[node];
    const int end = endA[node];

    float4 A0 = {0.f,0.f,0.f,0.f}, A1 = {0.f,0.f,0.f,0.f};
    float4 A2 = {0.f,0.f,0.f,0.f}, A3 = {0.f,0.f,0.f,0.f};
    float4 A4 = {0.f,0.f,0.f,0.f}, A5 = {0.f,0.f,0.f,0.f};
    float4 A6 = {0.f,0.f,0.f,0.f}, A7 = {0.f,0.f,0.f,0.f};

    for (int base = beg; base < end; base += 32) {
        const int nn = min(32, end - base);
        const int sidx = csr_src[base + min(l32, nn - 1)];
        int i = 0;
        for (; i + 8 <= nn; i += 8) {
            const int s0 = __shfl(sidx, i + 0, 32);
            const int s1 = __shfl(sidx, i + 1, 32);
            const int s2 = __shfl(sidx, i + 2, 32);
            const int s3 = __shfl(sidx, i + 3, 32);
            const int s4 = __shfl(sidx, i + 4, 32);
            const int s5 = __shfl(sidx, i + 5, 32);
            const int s6 = __shfl(sidx, i + 6, 32);
            const int s7 = __shfl(sidx, i + 7, 32);
            ushort4 v0 = *reinterpret_cast<const ushort4*>(xb + (size_t)s0 * IN_CH + c);
            ushort4 v1 = *reinterpret_cast<const ushort4*>(xb + (size_t)s1 * IN_CH + c);
            ushort4 v2 = *reinterpret_cast<const ushort4*>(xb + (size_t)s2 * IN_CH + c);
            ushort4 v3 = *reinterpret_cast<const ushort4*>(xb + (size_t)s3 * IN_CH + c);
            ushort4 v4 = *reinterpret_cast<const ushort4*>(xb + (size_t)s4 * IN_CH + c);
            ushort4 v5 = *reinterpret_cast<const ushort4*>(xb + (size_t)s5 * IN_CH + c);
            ushort4 v6 = *reinterpret_cast<const ushort4*>(xb + (size_t)s6 * IN_CH + c);
            ushort4 v7 = *reinterpret_cast<const ushort4*>(xb + (size_t)s7 * IN_CH + c);
            A0.x += b2f(v0.x); A0.y += b2f(v0.y); A0.z += b2f(v0.z); A0.w += b2f(v0.w);
            A1.x += b2f(v1.x); A1.y += b2f(v1.y); A1.z += b2f(v1.z); A1.w += b2f(v1.w);
            A2.x += b2f(v2.x); A2.y += b2f(v2.y); A2.z += b2f(v2.z); A2.w += b2f(v2.w);
            A3.x += b2f(v3.x); A3.y += b2f(v3.y); A3.z += b2f(v3.z); A3.w += b2f(v3.w);
            A4.x += b2f(v4.x); A4.y += b2f(v4.y); A4.z += b2f(v4.z); A4.w += b2f(v4.w);
            A5.x += b2f(v5.x); A5.y += b2f(v5.y); A5.z += b2f(v5.z); A5.w += b2f(v5.w);
            A6.x += b2f(v6.x); A6.y += b2f(v6.y); A6.z += b2f(v6.z); A6.w += b2f(v6.w);
            A7.x += b2f(v7.x); A7.y += b2f(v7.y); A7.z += b2f(v7.z); A7.w += b2f(v7.w);
        }
        for (; i < nn; ++i) {
            const int s = __shfl(sidx, i, 32);
            ushort4 v = *reinterpret_cast<const ushort4*>(xb + (size_t)s * IN_CH + c);
            A0.x += b2f(v.x); A0.y += b2f(v.y); A0.z += b2f(v.z); A0.w += b2f(v.w);
        }
    }

    const float a0 = ((A0.x + A1.x) + (A2.x + A3.x)) + ((A4.x + A5.x) + (A6.x + A7.x));
    const float a1 = ((A0.y + A1.y) + (A2.y + A3.y)) + ((A4.y + A5.y) + (A6.y + A7.y));
    const float a2 = ((A0.z + A1.z) + (A2.z + A3.z)) + ((A4.z + A5.z) + (A6.z + A7.z));
    const float a3 = ((A0.w + A1.w) + (A2.w + A3.w)) + ((A4.w + A5.w) + (A6.w + A7.w));

    const float scale = 1.0f + eps_p[0];
    ushort4 sv = *reinterpret_cast<const ushort4*>(xb + (size_t)node * IN_CH + c);
    ushort4 o;
    o.x = f2b(scale * b2f(sv.x) + a0);
    o.y = f2b(scale * b2f(sv.y) + a1);
    o.z = f2b(scale * b2f(sv.z) + a2);
    o.w = f2b(scale * b2f(sv.w) + a3);
    *reinterpret_cast<ushort4*>(h_in + (size_t)node * IN_CH + c) = o;
}

// ---------------------------------------------------------------------------
// Fused MLP (MFMA): out = log_softmax(relu(relu(h_in@W1+b1)@W2+b2))
// 512 thr = 8 waves x 16 rows. Phase 1 SWAPPED: acc = mfma(W1frag, hfrag)
// -> D[hc][row]; h1 stays in registers; 64-shfl permutation builds phase-2
// A-frags. LDS = 64 KB weights only -> 2 blocks/CU.
// ---------------------------------------------------------------------------
__global__ __launch_bounds__(512, 4) void mlp_fused(
    const ushort* __restrict__ h_in,
    const ushort* __restrict__ W1T,
    const ushort* __restrict__ W2T,
    const float* __restrict__ b1,
    const float* __restrict__ b2,
    float* __restrict__ out) {
    __shared__ ushort wbuf[32768];            // 64 KB weights (W1T, then W2T)
    const int t    = threadIdx.x;
    const int w    = t >> 6;
    const int lane = t & 63;
    const int lr   = lane & 15;               // n (row within wave)
    const int lk   = lane >> 4;               // q
    const int row0 = blockIdx.x * 128 + w * 16;
    const int arow = row0 + lr;
    const int arc  = arow < N_NODES ? arow : N_NODES - 1;
    const int sw = (lr & 7) << 3;             // read-side swizzle (halves)

    // ---- stage W1T (rows of 128 halves, swizzled); 64 halves/thread ----
    {
        const ushort* gw = W1T + t * 64;
        const int row = t >> 1;
        const int s = (row & 7) << 3;
        ushort* dstp = wbuf + row * 128;
        #pragma unroll
        for (int j = 0; j < 8; ++j) {
            short8 v = *reinterpret_cast<const short8*>(gw + j * 8);
            const int col = (t & 1) * 64 + j * 8;
            *reinterpret_cast<short8*>(dstp + (col ^ s)) = v;
        }
    }

    // h_in row fragments (phase-1 B operand), row = lr
    short8 a[4];
    const ushort* ap = h_in + (size_t)arc * IN_CH + lk * 8;
    #pragma unroll
    for (int kk = 0; kk < 4; ++kk)
        a[kk] = *reinterpret_cast<const short8*>(ap + kk * 32);

    __syncthreads();

    // ---- phase 1 (swapped): D[hc][row]; lane: row=lr, hc=ct*16+lk*4+r ----
    int pk[16][2];
    #pragma unroll
    for (int ct = 0; ct < 16; ++ct) {
        const ushort* bp = wbuf + (ct * 16 + lr) * 128;
        f32x4 acc = (f32x4){0.f, 0.f, 0.f, 0.f};
        #pragma unroll
        for (int kk = 0; kk < 4; ++kk) {
            short8 wf = *reinterpret_cast<const short8*>(bp + ((lk * 8 + kk * 32) ^ sw));
            acc = __builtin_amdgcn_mfma_f32_16x16x32_bf16(wf, a[kk], acc, 0, 0, 0);
        }
        const float4 bb = *reinterpret_cast<const float4*>(b1 + ct * 16 + lk * 4);
        const float v0 = fmaxf(acc[0] + bb.x, 0.0f);
        const float v1 = fmaxf(acc[1] + bb.y, 0.0f);
        const float v2 = fmaxf(acc[2] + bb.z, 0.0f);
        const float v3 = fmaxf(acc[3] + bb.w, 0.0f);
        pk[ct][0] = (int)f2b(v0) | ((int)f2b(v1) << 16);
        pk[ct][1] = (int)f2b(v2) | ((int)f2b(v3) << 16);
    }

    __syncthreads();   // all waves done reading W1 from wbuf

    // ---- stage W2T (rows of 256 halves, swizzled) ----
    {
        const ushort* gw = W2T + t * 64;
        const int row = t >> 2;
        const int s = (row & 7) << 3;
        ushort* dstp = wbuf + row * 256;
        #pragma unroll
        for (int j = 0; j < 8; ++j) {
            short8 v = *reinterpret_cast<const short8*>(gw + j * 8);
            const int col = (t & 3) * 64 + j * 8;
            *reinterpret_cast<short8*>(dstp + (col ^ s)) = v;
        }
    }

    // ---- in-register permutation: pk -> phase-2 A-frags (h1[row][hc]) ----
    short8 a2[8];
    #pragma unroll
    for (int kk2 = 0; kk2 < 8; ++kk2) {
        const int lo0 = pk[2 * kk2][0],     lo1 = pk[2 * kk2][1];
        const int hi0 = pk[2 * kk2 + 1][0], hi1 = pk[2 * kk2 + 1][1];
        union { int d[4]; short8 s8; } u;
        #pragma unroll
        for (int i = 0; i < 4; ++i) {
            const int srcLane = lr + 16 * ((2 * lk + (i >> 1)) & 3);
            const int vlo = __shfl((i & 1) ? lo1 : lo0, srcLane, 64);
            const int vhi = __shfl((i & 1) ? hi1 : hi0, srcLane, 64);
            u.d[i] = (lk < 2) ? vlo : vhi;
        }
        a2[kk2] = u.s8;
    }

    __syncthreads();   // W2 staged

    // ---- phase 2: out = lsm(relu(h1 @ W2 + b2)), 16 rows x 128 cols ----
    f32x4 acc2[8];
    #pragma unroll
    for (int ct = 0; ct < 8; ++ct) acc2[ct] = (f32x4){0.f, 0.f, 0.f, 0.f};

    #pragma unroll
    for (int ct = 0; ct < 8; ++ct) {
        const ushort* bp = wbuf + (ct * 16 + lr) * 256;
        #pragma unroll
        for (int kk = 0; kk < 8; ++kk) {
            short8 b = *reinterpret_cast<const short8*>(bp + ((lk * 8 + kk * 32) ^ sw));
            acc2[ct] = __builtin_amdgcn_mfma_f32_16x16x32_bf16(a2[kk], b, acc2[ct], 0, 0, 0);
        }
    }

    float bias[8];
    #pragma unroll
    for (int ct = 0; ct < 8; ++ct) bias[ct] = b2[ct * 16 + lr];

    const int orow0 = row0 + lk * 4;
    #pragma unroll
    for (int r = 0; r < 4; ++r) {
        float v[8];
        float m = -1e30f;
        #pragma unroll
        for (int ct = 0; ct < 8; ++ct) {
            v[ct] = fmaxf(acc2[ct][r] + bias[ct], 0.0f);
            m = fmaxf(m, v[ct]);
        }
        #pragma unroll
        for (int o = 1; o < 16; o <<= 1) m = fmaxf(m, __shfl_xor(m, o));
        float s = 0.0f;
        #pragma unroll
        for (int ct = 0; ct < 8; ++ct) s += __expf(v[ct] - m);
        #pragma unroll
        for (int o = 1; o < 16; o <<= 1) s += __shfl_xor(s, o);
        const float lse = m + __logf(s);
        const int orow = orow0 + r;
        if (orow < N_NODES) {
            #pragma unroll
            for (int ct = 0; ct < 8; ++ct)
                out[(size_t)orow * OUT_CH + ct * 16 + lr] = v[ct] - lse;
        }
    }
}

extern "C" void kernel_launch(void* const* d_in, const int* in_sizes, int n_in,
                              void* d_out, int out_size, void* d_ws, size_t ws_size,
                              hipStream_t stream) {
    const float* x    = (const float*)d_in[0];
    const int*   ei   = (const int*)d_in[1];
    const float* W1   = (const float*)d_in[2];
    const float* b1   = (const float*)d_in[3];
    const float* W2   = (const float*)d_in[4];
    const float* b2   = (const float*)d_in[5];
    const float* eps  = (const float*)d_in[6];
    float* out = (float*)d_out;

    // workspace layout
    ushort* xb   = (ushort*)d_ws;                          // 12.8M ushort
    ushort* h_in = xb + (size_t)N_NODES * IN_CH;           // 12.8M
    ushort* W1T  = h_in + (size_t)N_NODES * IN_CH;         // 32768
    ushort* W2T  = W1T + IN_CH * HID_CH;                   // 32768
    int* histT      = (int*)(W2T + HID_CH * OUT_CH);       // NBK*256
    int* blockBaseP = histT + NBK * BIN_BLOCKS;            // NBK*256
    int* bktTotal   = blockBaseP + NBK * BIN_BLOCKS;       // NBK
    int* begA       = bktTotal + NBK;                      // N_NODES
    int* endA       = begA + N_NODES;                      // N_NODES
    unsigned int* ebuf = (unsigned int*)(endA + N_NODES);  // NBK*BKT_CAP (12.8 MB)
    int* csr_src    = (int*)(ebuf + (size_t)NBK * BKT_CAP); // NBK*BKT_CAP (12.8 MB)

    const int* src = ei;
    const int* dst = ei + N_EDGES;

    prep_kernel<<<PREP_TOTAL + BIN_BLOCKS, 256, 0, stream>>>(
        x, W1, W2, dst, xb, W1T, W2T, histT);
    scanA_kernel<<<NBK, 256, 0, stream>>>(histT, blockBaseP, bktTotal);
    bin_kernel<<<BIN_BLOCKS, 256, 0, stream>>>(src, dst, blockBaseP, ebuf);
    group_kernel<<<NBK, 256, 0, stream>>>(ebuf, bktTotal, csr_src, begA, endA);
    gather_kernel<<<N_NODES / 8, 256, 0, stream>>>(xb, eps, begA, endA, csr_src, h_in);
    mlp_fused<<<(N_NODES + 127) / 128, 512, 0, stream>>>(h_in, W1T, W2T, b1, b2, out);
}

// Round 15
// 159.006 us; speedup vs baseline: 1.0734x; 1.0734x over previous
//
#include <hip/hip_runtime.h>

#define N_NODES 100000
#define IN_CH 128
#define HID_CH 256
#define OUT_CH 128
#define N_EDGES 1600000

#define NBK 782                                   // ceil(N_NODES/128) buckets of 128 nodes
#define BIN_BLOCKS 256
#define EPB (N_EDGES / BIN_BLOCKS)                // 6250 edges per bin block
#define BKT_CAP 4096                              // fixed bucket region (mean 2046, z~45)

typedef __attribute__((ext_vector_type(8))) short short8;
typedef __attribute__((ext_vector_type(4))) float f32x4;

// bf16 <-> f32 helpers (bit ops; finite data only)
__device__ __forceinline__ float b2f(ushort u) {
    unsigned int x = ((unsigned int)u) << 16;
    return __uint_as_float(x);
}
__device__ __forceinline__ ushort f2b(float f) {
    unsigned int u = __float_as_uint(f);
    u += 0x7FFFu + ((u >> 16) & 1u);   // round-to-nearest-even
    return (ushort)(u >> 16);
}

// ---------------------------------------------------------------------------
// Prep (+ fused ghist): x fp32 -> xb bf16 ; W1 -> W1T ; W2 -> W2T ;
// last 256 blocks: per-(block,bucket) dst histogram (transposed store).
// ---------------------------------------------------------------------------
#define PREP_X_BLOCKS 6250
#define PREP_W1_BLOCKS 128
#define PREP_W2_BLOCKS 128
#define PREP_TOTAL (PREP_X_BLOCKS + PREP_W1_BLOCKS + PREP_W2_BLOCKS)
__global__ __launch_bounds__(256) void prep_kernel(
    const float* __restrict__ x, const float* __restrict__ W1,
    const float* __restrict__ W2, const int* __restrict__ dst,
    ushort* __restrict__ xb, ushort* __restrict__ W1T,
    ushort* __restrict__ W2T, int* __restrict__ histT) {
    const int b = blockIdx.x;
    const int t = threadIdx.x;
    if (b < PREP_X_BLOCKS) {
        const size_t i = (size_t)b * 2048 + t * 8;
        float4 a = *reinterpret_cast<const float4*>(x + i);
        float4 c = *reinterpret_cast<const float4*>(x + i + 4);
        ushort v[8] = {f2b(a.x), f2b(a.y), f2b(a.z), f2b(a.w),
                       f2b(c.x), f2b(c.y), f2b(c.z), f2b(c.w)};
        *reinterpret_cast<short8*>(xb + i) = *reinterpret_cast<short8*>(v);
    } else if (b < PREP_X_BLOCKS + PREP_W1_BLOCKS) {
        const int i = (b - PREP_X_BLOCKS) * 256 + t;     // oc*128 + k
        const int oc = i >> 7, k = i & 127;
        W1T[i] = f2b(W1[k * HID_CH + oc]);
    } else if (b < PREP_TOTAL) {
        const int i = (b - PREP_X_BLOCKS - PREP_W1_BLOCKS) * 256 + t; // oc*256+k
        const int oc = i >> 8, k = i & 255;
        W2T[i] = f2b(W2[k * OUT_CH + oc]);
    } else {
        __shared__ int h[NBK];
        const int bb = b - PREP_TOTAL;
        for (int k = t; k < NBK; k += 256) h[k] = 0;
        __syncthreads();
        const int base = bb * EPB;
        for (int i = t; i < EPB; i += 256)
            atomicAdd(&h[dst[base + i] >> 7], 1);
        __syncthreads();
        for (int k = t; k < NBK; k += 256) histT[k * BIN_BLOCKS + bb] = h[k];
    }
}

// ---------------------------------------------------------------------------
// Per-bucket exclusive scan over the 256 block counts (bucket regions fixed).
// ---------------------------------------------------------------------------
__global__ __launch_bounds__(256) void scanA_kernel(
    const int* __restrict__ histT, int* __restrict__ blockBaseP,
    int* __restrict__ bktTotal) {
    __shared__ int ts[256];
    const int bk = blockIdx.x, t = threadIdx.x;
    const int v = histT[bk * BIN_BLOCKS + t];
    ts[t] = v;
    __syncthreads();
    #pragma unroll
    for (int o = 1; o < 256; o <<= 1) {
        int add = (t >= o) ? ts[t - o] : 0;
        __syncthreads();
        ts[t] += add;
        __syncthreads();
    }
    blockBaseP[bk * BIN_BLOCKS + t] = ts[t] - v;
    if (t == 255) bktTotal[bk] = ts[255];
}

// ---------------------------------------------------------------------------
// bin: LDS-sort the block's EPB edges by bucket, then flush each bucket-run
// CONTIGUOUSLY into its (block,bucket) slot -> line-friendly writes.
// ---------------------------------------------------------------------------
__global__ __launch_bounds__(256) void bin_kernel(
    const int* __restrict__ src, const int* __restrict__ dst,
    const int* __restrict__ blockBaseP,
    unsigned int* __restrict__ ebuf) {
    __shared__ unsigned int srt[EPB];     // 25 KB sorted entries
    __shared__ int h[NBK];                // counts -> local exclusive base
    __shared__ int cur[NBK];
    __shared__ int part[256];
    const int b = blockIdx.x, t = threadIdx.x;
    for (int k = t; k < NBK; k += 256) h[k] = 0;
    __syncthreads();
    const int ebase = b * EPB;
    for (int i = t; i < EPB; i += 256)
        atomicAdd(&h[dst[ebase + i] >> 7], 1);
    __syncthreads();
    // chunked exclusive scan: thread t owns bins 4t..4t+3
    const int k0 = t * 4;
    const int s0 = (k0 + 0 < NBK) ? h[k0 + 0] : 0;
    const int s1 = (k0 + 1 < NBK) ? h[k0 + 1] : 0;
    const int s2 = (k0 + 2 < NBK) ? h[k0 + 2] : 0;
    const int s3 = (k0 + 3 < NBK) ? h[k0 + 3] : 0;
    const int tot = s0 + s1 + s2 + s3;
    part[t] = tot;
    __syncthreads();
    #pragma unroll
    for (int o = 1; o < 256; o <<= 1) {
        int add = (t >= o) ? part[t - o] : 0;
        __syncthreads();
        part[t] += add;
        __syncthreads();
    }
    const int excl = part[t] - tot;
    if (k0 + 0 < NBK) { h[k0 + 0] = excl;               cur[k0 + 0] = excl; }
    if (k0 + 1 < NBK) { h[k0 + 1] = excl + s0;          cur[k0 + 1] = excl + s0; }
    if (k0 + 2 < NBK) { h[k0 + 2] = excl + s0 + s1;     cur[k0 + 2] = excl + s0 + s1; }
    if (k0 + 3 < NBK) { h[k0 + 3] = excl + s0 + s1 + s2; cur[k0 + 3] = excl + s0 + s1 + s2; }
    __syncthreads();
    // scatter into LDS sorted order
    for (int i = t; i < EPB; i += 256) {
        const int d = dst[ebase + i];
        const int s = src[ebase + i];
        const int bk = d >> 7;
        const int p = atomicAdd(&cur[bk], 1);
        srt[p] = ((unsigned int)(d & 127) << 17) | (unsigned int)s;
    }
    __syncthreads();
    // flush runs: thread t flushes its 4 bins contiguously
    #pragma unroll
    for (int j = 0; j < 4; ++j) {
        const int k = k0 + j;
        if (k < NBK) {
            const int lb = h[k];
            const int le = cur[k];
            unsigned int* gp = ebuf + (size_t)k * BKT_CAP
                             + blockBaseP[k * BIN_BLOCKS + b];
            for (int p = lb; p < le; ++p) gp[p - lb] = srt[p];
        }
    }
}

// ---------------------------------------------------------------------------
// group: node-sort each bucket in LDS, stream csr_src out COALESCED.
// Writes per-node beg/end.
// ---------------------------------------------------------------------------
__global__ __launch_bounds__(256) void group_kernel(
    const unsigned int* __restrict__ ebuf,
    const int* __restrict__ bktTotal,
    int* __restrict__ csr_src, int* __restrict__ begA, int* __restrict__ endA) {
    __shared__ unsigned int ein[BKT_CAP];   // 16 KB
    __shared__ int srt[BKT_CAP];            // 16 KB
    __shared__ int hist[128];
    __shared__ int cur[128];
    const int bk = blockIdx.x, t = threadIdx.x;
    if (t < 128) hist[t] = 0;
    __syncthreads();
    const int start = bk * BKT_CAP;
    const int cnt = min(bktTotal[bk], BKT_CAP);
    for (int i = t; i < cnt; i += 256) {
        const unsigned int e = ebuf[start + i];
        ein[i] = e;
        atomicAdd(&hist[e >> 17], 1);
    }
    __syncthreads();
    int v = (t < 128) ? hist[t] : 0;
    #pragma unroll
    for (int o = 1; o < 128; o <<= 1) {
        int add = (t < 128 && t >= o) ? hist[t - o] : 0;
        __syncthreads();
        if (t < 128) hist[t] += add;
        __syncthreads();
    }
    if (t < 128) {
        const int excl = hist[t] - v;
        cur[t] = excl;
        const int node = bk * 128 + t;
        if (node < N_NODES) {
            begA[node] = start + excl;
            endA[node] = start + hist[t];   // inclusive scan = end
        }
    }
    __syncthreads();
    for (int i = t; i < cnt; i += 256) {
        const unsigned int e = ein[i];
        const int dl = e >> 17;
        const int p = atomicAdd(&cur[dl], 1);
        srt[p] = (int)(e & 0x1FFFF);
    }
    __syncthreads();
    for (int i = t; i < cnt; i += 256)
        csr_src[start + i] = srt[i];        // fully coalesced
}

// ---------------------------------------------------------------------------
// Gather-aggregate fused with GIN self-term (bf16 rows, fp32 accum):
//   h_in[i] = bf16( (1+eps)*x[i] + sum_{j in N(i)} x[j] )
// R13 structure (fastest measured): 8 nodes/block, 32 threads/node, ushort4
// per thread; 32-edge tiles, FOUR independent accumulator chains via shfl.
// ---------------------------------------------------------------------------
__global__ __launch_bounds__(256) void gather_kernel(
    const ushort* __restrict__ xb,
    const float* __restrict__ eps_p,
    const int* __restrict__ begA,
    const int* __restrict__ endA,
    const int* __restrict__ csr_src,
    ushort* __restrict__ h_in) {
    const int node = blockIdx.x * 8 + (threadIdx.x >> 5);
    const int l32 = threadIdx.x & 31;
    const int c = l32 * 4;
    const int beg = begA[node];
    const int end = endA[node];

    float4 A0 = {0.f,0.f,0.f,0.f}, A1 = {0.f,0.f,0.f,0.f};
    float4 A2 = {0.f,0.f,0.f,0.f}, A3 = {0.f,0.f,0.f,0.f};

    for (int base = beg; base < end; base += 32) {
        const int nn = min(32, end - base);
        const int sidx = csr_src[base + min(l32, nn - 1)];
        int i = 0;
        for (; i + 4 <= nn; i += 4) {
            const int s0 = __shfl(sidx, i + 0, 32);
            const int s1 = __shfl(sidx, i + 1, 32);
            const int s2 = __shfl(sidx, i + 2, 32);
            const int s3 = __shfl(sidx, i + 3, 32);
            ushort4 v0 = *reinterpret_cast<const ushort4*>(xb + (size_t)s0 * IN_CH + c);
            ushort4 v1 = *reinterpret_cast<const ushort4*>(xb + (size_t)s1 * IN_CH + c);
            ushort4 v2 = *reinterpret_cast<const ushort4*>(xb + (size_t)s2 * IN_CH + c);
            ushort4 v3 = *reinterpret_cast<const ushort4*>(xb + (size_t)s3 * IN_CH + c);
            A0.x += b2f(v0.x); A0.y += b2f(v0.y); A0.z += b2f(v0.z); A0.w += b2f(v0.w);
            A1.x += b2f(v1.x); A1.y += b2f(v1.y); A1.z += b2f(v1.z); A1.w += b2f(v1.w);
            A2.x += b2f(v2.x); A2.y += b2f(v2.y); A2.z += b2f(v2.z); A2.w += b2f(v2.w);
            A3.x += b2f(v3.x); A3.y += b2f(v3.y); A3.z += b2f(v3.z); A3.w += b2f(v3.w);
        }
        for (; i < nn; ++i) {
            const int s = __shfl(sidx, i, 32);
            ushort4 v = *reinterpret_cast<const ushort4*>(xb + (size_t)s * IN_CH + c);
            A0.x += b2f(v.x); A0.y += b2f(v.y); A0.z += b2f(v.z); A0.w += b2f(v.w);
        }
    }

    const float a0 = A0.x + A1.x + A2.x + A3.x;
    const float a1 = A0.y + A1.y + A2.y + A3.y;
    const float a2 = A0.z + A1.z + A2.z + A3.z;
    const float a3 = A0.w + A1.w + A2.w + A3.w;

    const float scale = 1.0f + eps_p[0];
    ushort4 sv = *reinterpret_cast<const ushort4*>(xb + (size_t)node * IN_CH + c);
    ushort4 o;
    o.x = f2b(scale * b2f(sv.x) + a0);
    o.y = f2b(scale * b2f(sv.y) + a1);
    o.z = f2b(scale * b2f(sv.z) + a2);
    o.w = f2b(scale * b2f(sv.w) + a3);
    *reinterpret_cast<ushort4*>(h_in + (size_t)node * IN_CH + c) = o;
}

// ---------------------------------------------------------------------------
// Fused MLP (MFMA): out = log_softmax(relu(relu(h_in@W1+b1)@W2+b2))
// 512 thr = 8 waves x 16 rows. Phase 1 SWAPPED: acc = mfma(W1frag, hfrag)
// -> D[hc][row]; h1 stays in registers; 64-shfl permutation builds phase-2
// A-frags. LDS = 64 KB weights only -> 2 blocks/CU.
// ---------------------------------------------------------------------------
__global__ __launch_bounds__(512, 4) void mlp_fused(
    const ushort* __restrict__ h_in,
    const ushort* __restrict__ W1T,
    const ushort* __restrict__ W2T,
    const float* __restrict__ b1,
    const float* __restrict__ b2,
    float* __restrict__ out) {
    __shared__ ushort wbuf[32768];            // 64 KB weights (W1T, then W2T)
    const int t    = threadIdx.x;
    const int w    = t >> 6;
    const int lane = t & 63;
    const int lr   = lane & 15;               // n (row within wave)
    const int lk   = lane >> 4;               // q
    const int row0 = blockIdx.x * 128 + w * 16;
    const int arow = row0 + lr;
    const int arc  = arow < N_NODES ? arow : N_NODES - 1;
    const int sw = (lr & 7) << 3;             // read-side swizzle (halves)

    // ---- stage W1T (rows of 128 halves, swizzled); 64 halves/thread ----
    {
        const ushort* gw = W1T + t * 64;
        const int row = t >> 1;
        const int s = (row & 7) << 3;
        ushort* dstp = wbuf + row * 128;
        #pragma unroll
        for (int j = 0; j < 8; ++j) {
            short8 v = *reinterpret_cast<const short8*>(gw + j * 8);
            const int col = (t & 1) * 64 + j * 8;
            *reinterpret_cast<short8*>(dstp + (col ^ s)) = v;
        }
    }

    // h_in row fragments (phase-1 B operand), row = lr
    short8 a[4];
    const ushort* ap = h_in + (size_t)arc * IN_CH + lk * 8;
    #pragma unroll
    for (int kk = 0; kk < 4; ++kk)
        a[kk] = *reinterpret_cast<const short8*>(ap + kk * 32);

    __syncthreads();

    // ---- phase 1 (swapped): D[hc][row]; lane: row=lr, hc=ct*16+lk*4+r ----
    int pk[16][2];
    #pragma unroll
    for (int ct = 0; ct < 16; ++ct) {
        const ushort* bp = wbuf + (ct * 16 + lr) * 128;
        f32x4 acc = (f32x4){0.f, 0.f, 0.f, 0.f};
        #pragma unroll
        for (int kk = 0; kk < 4; ++kk) {
            short8 wf = *reinterpret_cast<const short8*>(bp + ((lk * 8 + kk * 32) ^ sw));
            acc = __builtin_amdgcn_mfma_f32_16x16x32_bf16(wf, a[kk], acc, 0, 0, 0);
        }
        const float4 bb = *reinterpret_cast<const float4*>(b1 + ct * 16 + lk * 4);
        const float v0 = fmaxf(acc[0] + bb.x, 0.0f);
        const float v1 = fmaxf(acc[1] + bb.y, 0.0f);
        const float v2 = fmaxf(acc[2] + bb.z, 0.0f);
        const float v3 = fmaxf(acc[3] + bb.w, 0.0f);
        pk[ct][0] = (int)f2b(v0) | ((int)f2b(v1) << 16);
        pk[ct][1] = (int)f2b(v2) | ((int)f2b(v3) << 16);
    }

    __syncthreads();   // all waves done reading W1 from wbuf

    // ---- stage W2T (rows of 256 halves, swizzled) ----
    {
        const ushort* gw = W2T + t * 64;
        const int row = t >> 2;
        const int s = (row & 7) << 3;
        ushort* dstp = wbuf + row * 256;
        #pragma unroll
        for (int j = 0; j < 8; ++j) {
            short8 v = *reinterpret_cast<const short8*>(gw + j * 8);
            const int col = (t & 3) * 64 + j * 8;
            *reinterpret_cast<short8*>(dstp + (col ^ s)) = v;
        }
    }

    // ---- in-register permutation: pk -> phase-2 A-frags (h1[row][hc]) ----
    short8 a2[8];
    #pragma unroll
    for (int kk2 = 0; kk2 < 8; ++kk2) {
        const int lo0 = pk[2 * kk2][0],     lo1 = pk[2 * kk2][1];
        const int hi0 = pk[2 * kk2 + 1][0], hi1 = pk[2 * kk2 + 1][1];
        union { int d[4]; short8 s8; } u;
        #pragma unroll
        for (int i = 0; i < 4; ++i) {
            const int srcLane = lr + 16 * ((2 * lk + (i >> 1)) & 3);
            const int vlo = __shfl((i & 1) ? lo1 : lo0, srcLane, 64);
            const int vhi = __shfl((i & 1) ? hi1 : hi0, srcLane, 64);
            u.d[i] = (lk < 2) ? vlo : vhi;
        }
        a2[kk2] = u.s8;
    }

    __syncthreads();   // W2 staged

    // ---- phase 2: out = lsm(relu(h1 @ W2 + b2)), 16 rows x 128 cols ----
    f32x4 acc2[8];
    #pragma unroll
    for (int ct = 0; ct < 8; ++ct) acc2[ct] = (f32x4){0.f, 0.f, 0.f, 0.f};

    #pragma unroll
    for (int ct = 0; ct < 8; ++ct) {
        const ushort* bp = wbuf + (ct * 16 + lr) * 256;
        #pragma unroll
        for (int kk = 0; kk < 8; ++kk) {
            short8 b = *reinterpret_cast<const short8*>(bp + ((lk * 8 + kk * 32) ^ sw));
            acc2[ct] = __builtin_amdgcn_mfma_f32_16x16x32_bf16(a2[kk], b, acc2[ct], 0, 0, 0);
        }
    }

    float bias[8];
    #pragma unroll
    for (int ct = 0; ct < 8; ++ct) bias[ct] = b2[ct * 16 + lr];

    const int orow0 = row0 + lk * 4;
    #pragma unroll
    for (int r = 0; r < 4; ++r) {
        float v[8];
        float m = -1e30f;
        #pragma unroll
        for (int ct = 0; ct < 8; ++ct) {
            v[ct] = fmaxf(acc2[ct][r] + bias[ct], 0.0f);
            m = fmaxf(m, v[ct]);
        }
        #pragma unroll
        for (int o = 1; o < 16; o <<= 1) m = fmaxf(m, __shfl_xor(m, o));
        float s = 0.0f;
        #pragma unroll
        for (int ct = 0; ct < 8; ++ct) s += __expf(v[ct] - m);
        #pragma unroll
        for (int o = 1; o < 16; o <<= 1) s += __shfl_xor(s, o);
        const float lse = m + __logf(s);
        const int orow = orow0 + r;
        if (orow < N_NODES) {
            #pragma unroll
            for (int ct = 0; ct < 8; ++ct)
                out[(size_t)orow * OUT_CH + ct * 16 + lr] = v[ct] - lse;
        }
    }
}

extern "C" void kernel_launch(void* const* d_in, const int* in_sizes, int n_in,
                              void* d_out, int out_size, void* d_ws, size_t ws_size,
                              hipStream_t stream) {
    const float* x    = (const float*)d_in[0];
    const int*   ei   = (const int*)d_in[1];
    const float* W1   = (const float*)d_in[2];
    const float* b1   = (const float*)d_in[3];
    const float* W2   = (const float*)d_in[4];
    const float* b2   = (const float*)d_in[5];
    const float* eps  = (const float*)d_in[6];
    float* out = (float*)d_out;

    // workspace layout
    ushort* xb   = (ushort*)d_ws;                          // 12.8M ushort
    ushort* h_in = xb + (size_t)N_NODES * IN_CH;           // 12.8M
    ushort* W1T  = h_in + (size_t)N_NODES * IN_CH;         // 32768
    ushort* W2T  = W1T + IN_CH * HID_CH;                   // 32768
    int* histT      = (int*)(W2T + HID_CH * OUT_CH);       // NBK*256
    int* blockBaseP = histT + NBK * BIN_BLOCKS;            // NBK*256
    int* bktTotal   = blockBaseP + NBK * BIN_BLOCKS;       // NBK
    int* begA       = bktTotal + NBK;                      // N_NODES
    int* endA       = begA + N_NODES;                      // N_NODES
    unsigned int* ebuf = (unsigned int*)(endA + N_NODES);  // NBK*BKT_CAP (12.8 MB)
    int* csr_src    = (int*)(ebuf + (size_t)NBK * BKT_CAP); // NBK*BKT_CAP (12.8 MB)

    const int* src = ei;
    const int* dst = ei + N_EDGES;

    prep_kernel<<<PREP_TOTAL + BIN_BLOCKS, 256, 0, stream>>>(
        x, W1, W2, dst, xb, W1T, W2T, histT);
    scanA_kernel<<<NBK, 256, 0, stream>>>(histT, blockBaseP, bktTotal);
    bin_kernel<<<BIN_BLOCKS, 256, 0, stream>>>(src, dst, blockBaseP, ebuf);
    group_kernel<<<NBK, 256, 0, stream>>>(ebuf, bktTotal, csr_src, begA, endA);
    gather_kernel<<<N_NODES / 8, 256, 0, stream>>>(xb, eps, begA, endA, csr_src, h_in);
    mlp_fused<<<(N_NODES + 127) / 128, 512, 0, stream>>>(h_in, W1T, W2T, b1, b2, out);
}

// Round 16
// 156.969 us; speedup vs baseline: 1.0873x; 1.0130x over previous
//
#include <hip/hip_runtime.h>

#define N_NODES 100000
#define IN_CH 128
#define HID_CH 256
#define OUT_CH 128
#define N_EDGES 1600000

#define NBK 782                                   // ceil(N_NODES/128) buckets of 128 nodes
#define BIN_BLOCKS 256
#define EPB (N_EDGES / BIN_BLOCKS)                // 6250 edges per bin block
#define BKT_CAP 4096                              // fixed bucket region (mean 2046, z~45)

typedef __attribute__((ext_vector_type(8))) short short8;
typedef __attribute__((ext_vector_type(4))) float f32x4;

// bf16 <-> f32 helpers (bit ops; finite data only)
__device__ __forceinline__ float b2f(ushort u) {
    unsigned int x = ((unsigned int)u) << 16;
    return __uint_as_float(x);
}
__device__ __forceinline__ ushort f2b(float f) {
    unsigned int u = __float_as_uint(f);
    u += 0x7FFFu + ((u >> 16) & 1u);   // round-to-nearest-even
    return (ushort)(u >> 16);
}

// ---------------------------------------------------------------------------
// Prep (+ fused ghist): x fp32 -> xb bf16 ; W1 -> W1T ; W2 -> W2T ;
// last 256 blocks: per-(block,bucket) dst histogram (transposed store).
// ---------------------------------------------------------------------------
#define PREP_X_BLOCKS 6250
#define PREP_W1_BLOCKS 128
#define PREP_W2_BLOCKS 128
#define PREP_TOTAL (PREP_X_BLOCKS + PREP_W1_BLOCKS + PREP_W2_BLOCKS)
__global__ __launch_bounds__(256) void prep_kernel(
    const float* __restrict__ x, const float* __restrict__ W1,
    const float* __restrict__ W2, const int* __restrict__ dst,
    ushort* __restrict__ xb, ushort* __restrict__ W1T,
    ushort* __restrict__ W2T, int* __restrict__ histT) {
    const int b = blockIdx.x;
    const int t = threadIdx.x;
    if (b < PREP_X_BLOCKS) {
        const size_t i = (size_t)b * 2048 + t * 8;
        float4 a = *reinterpret_cast<const float4*>(x + i);
        float4 c = *reinterpret_cast<const float4*>(x + i + 4);
        ushort v[8] = {f2b(a.x), f2b(a.y), f2b(a.z), f2b(a.w),
                       f2b(c.x), f2b(c.y), f2b(c.z), f2b(c.w)};
        *reinterpret_cast<short8*>(xb + i) = *reinterpret_cast<short8*>(v);
    } else if (b < PREP_X_BLOCKS + PREP_W1_BLOCKS) {
        const int i = (b - PREP_X_BLOCKS) * 256 + t;     // oc*128 + k
        const int oc = i >> 7, k = i & 127;
        W1T[i] = f2b(W1[k * HID_CH + oc]);
    } else if (b < PREP_TOTAL) {
        const int i = (b - PREP_X_BLOCKS - PREP_W1_BLOCKS) * 256 + t; // oc*256+k
        const int oc = i >> 8, k = i & 255;
        W2T[i] = f2b(W2[k * OUT_CH + oc]);
    } else {
        __shared__ int h[NBK];
        const int bb = b - PREP_TOTAL;
        for (int k = t; k < NBK; k += 256) h[k] = 0;
        __syncthreads();
        const int base = bb * EPB;
        for (int i = t; i < EPB; i += 256)
            atomicAdd(&h[dst[base + i] >> 7], 1);
        __syncthreads();
        for (int k = t; k < NBK; k += 256) histT[k * BIN_BLOCKS + bb] = h[k];
    }
}

// ---------------------------------------------------------------------------
// Per-bucket exclusive scan over the 256 block counts (bucket regions fixed).
// ---------------------------------------------------------------------------
__global__ __launch_bounds__(256) void scanA_kernel(
    const int* __restrict__ histT, int* __restrict__ blockBaseP,
    int* __restrict__ bktTotal) {
    __shared__ int ts[256];
    const int bk = blockIdx.x, t = threadIdx.x;
    const int v = histT[bk * BIN_BLOCKS + t];
    ts[t] = v;
    __syncthreads();
    #pragma unroll
    for (int o = 1; o < 256; o <<= 1) {
        int add = (t >= o) ? ts[t - o] : 0;
        __syncthreads();
        ts[t] += add;
        __syncthreads();
    }
    blockBaseP[bk * BIN_BLOCKS + t] = ts[t] - v;
    if (t == 255) bktTotal[bk] = ts[255];
}

// ---------------------------------------------------------------------------
// bin: LDS-sort the block's EPB edges by bucket, then flush each bucket-run
// CONTIGUOUSLY into its (block,bucket) slot -> line-friendly writes.
// ---------------------------------------------------------------------------
__global__ __launch_bounds__(256) void bin_kernel(
    const int* __restrict__ src, const int* __restrict__ dst,
    const int* __restrict__ blockBaseP,
    unsigned int* __restrict__ ebuf) {
    __shared__ unsigned int srt[EPB];     // 25 KB sorted entries
    __shared__ int h[NBK];                // counts -> local exclusive base
    __shared__ int cur[NBK];
    __shared__ int part[256];
    const int b = blockIdx.x, t = threadIdx.x;
    for (int k = t; k < NBK; k += 256) h[k] = 0;
    __syncthreads();
    const int ebase = b * EPB;
    for (int i = t; i < EPB; i += 256)
        atomicAdd(&h[dst[ebase + i] >> 7], 1);
    __syncthreads();
    // chunked exclusive scan: thread t owns bins 4t..4t+3
    const int k0 = t * 4;
    const int s0 = (k0 + 0 < NBK) ? h[k0 + 0] : 0;
    const int s1 = (k0 + 1 < NBK) ? h[k0 + 1] : 0;
    const int s2 = (k0 + 2 < NBK) ? h[k0 + 2] : 0;
    const int s3 = (k0 + 3 < NBK) ? h[k0 + 3] : 0;
    const int tot = s0 + s1 + s2 + s3;
    part[t] = tot;
    __syncthreads();
    #pragma unroll
    for (int o = 1; o < 256; o <<= 1) {
        int add = (t >= o) ? part[t - o] : 0;
        __syncthreads();
        part[t] += add;
        __syncthreads();
    }
    const int excl = part[t] - tot;
    if (k0 + 0 < NBK) { h[k0 + 0] = excl;               cur[k0 + 0] = excl; }
    if (k0 + 1 < NBK) { h[k0 + 1] = excl + s0;          cur[k0 + 1] = excl + s0; }
    if (k0 + 2 < NBK) { h[k0 + 2] = excl + s0 + s1;     cur[k0 + 2] = excl + s0 + s1; }
    if (k0 + 3 < NBK) { h[k0 + 3] = excl + s0 + s1 + s2; cur[k0 + 3] = excl + s0 + s1 + s2; }
    __syncthreads();
    // scatter into LDS sorted order
    for (int i = t; i < EPB; i += 256) {
        const int d = dst[ebase + i];
        const int s = src[ebase + i];
        const int bk = d >> 7;
        const int p = atomicAdd(&cur[bk], 1);
        srt[p] = ((unsigned int)(d & 127) << 17) | (unsigned int)s;
    }
    __syncthreads();
    // flush runs: thread t flushes its 4 bins contiguously
    #pragma unroll
    for (int j = 0; j < 4; ++j) {
        const int k = k0 + j;
        if (k < NBK) {
            const int lb = h[k];
            const int le = cur[k];
            unsigned int* gp = ebuf + (size_t)k * BKT_CAP
                             + blockBaseP[k * BIN_BLOCKS + b];
            for (int p = lb; p < le; ++p) gp[p - lb] = srt[p];
        }
    }
}

// ---------------------------------------------------------------------------
// group: node-sort each bucket in LDS, stream csr_src out COALESCED.
// Writes per-node beg/end.
// ---------------------------------------------------------------------------
__global__ __launch_bounds__(256) void group_kernel(
    const unsigned int* __restrict__ ebuf,
    const int* __restrict__ bktTotal,
    int* __restrict__ csr_src, int* __restrict__ begA, int* __restrict__ endA) {
    __shared__ unsigned int ein[BKT_CAP];   // 16 KB
    __shared__ int srt[BKT_CAP];            // 16 KB
    __shared__ int hist[128];
    __shared__ int cur[128];
    const int bk = blockIdx.x, t = threadIdx.x;
    if (t < 128) hist[t] = 0;
    __syncthreads();
    const int start = bk * BKT_CAP;
    const int cnt = min(bktTotal[bk], BKT_CAP);
    for (int i = t; i < cnt; i += 256) {
        const unsigned int e = ebuf[start + i];
        ein[i] = e;
        atomicAdd(&hist[e >> 17], 1);
    }
    __syncthreads();
    int v = (t < 128) ? hist[t] : 0;
    #pragma unroll
    for (int o = 1; o < 128; o <<= 1) {
        int add = (t < 128 && t >= o) ? hist[t - o] : 0;
        __syncthreads();
        if (t < 128) hist[t] += add;
        __syncthreads();
    }
    if (t < 128) {
        const int excl = hist[t] - v;
        cur[t] = excl;
        const int node = bk * 128 + t;
        if (node < N_NODES) {
            begA[node] = start + excl;
            endA[node] = start + hist[t];   // inclusive scan = end
        }
    }
    __syncthreads();
    for (int i = t; i < cnt; i += 256) {
        const unsigned int e = ein[i];
        const int dl = e >> 17;
        const int p = atomicAdd(&cur[dl], 1);
        srt[p] = (int)(e & 0x1FFFF);
    }
    __syncthreads();
    for (int i = t; i < cnt; i += 256)
        csr_src[start + i] = srt[i];        // fully coalesced
}

// ---------------------------------------------------------------------------
// Gather-aggregate fused with GIN self-term (bf16 rows, fp32 accum):
//   h_in[i] = bf16( (1+eps)*x[i] + sum_{j in N(i)} x[j] )
// 8 nodes/block, 32 threads/node, ushort4 per thread; 32-edge tiles,
// FOUR independent accumulator chains via shfl (measured optimum).
// ---------------------------------------------------------------------------
__global__ __launch_bounds__(256) void gather_kernel(
    const ushort* __restrict__ xb,
    const float* __restrict__ eps_p,
    const int* __restrict__ begA,
    const int* __restrict__ endA,
    const int* __restrict__ csr_src,
    ushort* __restrict__ h_in) {
    const int node = blockIdx.x * 8 + (threadIdx.x >> 5);
    const int l32 = threadIdx.x & 31;
    const int c = l32 * 4;
    const int beg = begA[node];
    const int end = endA[node];

    float4 A0 = {0.f,0.f,0.f,0.f}, A1 = {0.f,0.f,0.f,0.f};
    float4 A2 = {0.f,0.f,0.f,0.f}, A3 = {0.f,0.f,0.f,0.f};

    for (int base = beg; base < end; base += 32) {
        const int nn = min(32, end - base);
        const int sidx = csr_src[base + min(l32, nn - 1)];
        int i = 0;
        for (; i + 4 <= nn; i += 4) {
            const int s0 = __shfl(sidx, i + 0, 32);
            const int s1 = __shfl(sidx, i + 1, 32);
            const int s2 = __shfl(sidx, i + 2, 32);
            const int s3 = __shfl(sidx, i + 3, 32);
            ushort4 v0 = *reinterpret_cast<const ushort4*>(xb + (size_t)s0 * IN_CH + c);
            ushort4 v1 = *reinterpret_cast<const ushort4*>(xb + (size_t)s1 * IN_CH + c);
            ushort4 v2 = *reinterpret_cast<const ushort4*>(xb + (size_t)s2 * IN_CH + c);
            ushort4 v3 = *reinterpret_cast<const ushort4*>(xb + (size_t)s3 * IN_CH + c);
            A0.x += b2f(v0.x); A0.y += b2f(v0.y); A0.z += b2f(v0.z); A0.w += b2f(v0.w);
            A1.x += b2f(v1.x); A1.y += b2f(v1.y); A1.z += b2f(v1.z); A1.w += b2f(v1.w);
            A2.x += b2f(v2.x); A2.y += b2f(v2.y); A2.z += b2f(v2.z); A2.w += b2f(v2.w);
            A3.x += b2f(v3.x); A3.y += b2f(v3.y); A3.z += b2f(v3.z); A3.w += b2f(v3.w);
        }
        for (; i < nn; ++i) {
            const int s = __shfl(sidx, i, 32);
            ushort4 v = *reinterpret_cast<const ushort4*>(xb + (size_t)s * IN_CH + c);
            A0.x += b2f(v.x); A0.y += b2f(v.y); A0.z += b2f(v.z); A0.w += b2f(v.w);
        }
    }

    const float a0 = A0.x + A1.x + A2.x + A3.x;
    const float a1 = A0.y + A1.y + A2.y + A3.y;
    const float a2 = A0.z + A1.z + A2.z + A3.z;
    const float a3 = A0.w + A1.w + A2.w + A3.w;

    const float scale = 1.0f + eps_p[0];
    ushort4 sv = *reinterpret_cast<const ushort4*>(xb + (size_t)node * IN_CH + c);
    ushort4 o;
    o.x = f2b(scale * b2f(sv.x) + a0);
    o.y = f2b(scale * b2f(sv.y) + a1);
    o.z = f2b(scale * b2f(sv.z) + a2);
    o.w = f2b(scale * b2f(sv.w) + a3);
    *reinterpret_cast<ushort4*>(h_in + (size_t)node * IN_CH + c) = o;
}

// ---------------------------------------------------------------------------
// Fused MLP (MFMA): out = log_softmax(relu(relu(h_in@W1+b1)@W2+b2))
// 256 thr = 4 waves; each wave owns TWO 16-row groups (32 rows) so every
// weight fragment read from LDS feeds two MFMAs (halves per-row LDS issue,
// the measured bottleneck). Phase 1 swapped (mfma(W1frag,hfrag) -> D[hc][row]);
// h1 in registers; verified 64-shfl permutation x2 builds phase-2 A-frags.
// LDS = 64 KB weights only.
// ---------------------------------------------------------------------------
__global__ __launch_bounds__(256, 2) void mlp_fused(
    const ushort* __restrict__ h_in,
    const ushort* __restrict__ W1T,
    const ushort* __restrict__ W2T,
    const float* __restrict__ b1,
    const float* __restrict__ b2,
    float* __restrict__ out) {
    __shared__ ushort wbuf[32768];            // 64 KB weights (W1T, then W2T)
    const int t    = threadIdx.x;
    const int w    = t >> 6;
    const int lane = t & 63;
    const int lr   = lane & 15;               // row-within-group / col idx
    const int lk   = lane >> 4;               // q
    const int row0 = blockIdx.x * 128 + w * 32;
    const int arowA = row0 + lr;
    const int arowB = row0 + 16 + lr;
    const int arcA = arowA < N_NODES ? arowA : N_NODES - 1;
    const int arcB = arowB < N_NODES ? arowB : N_NODES - 1;
    const int sw = (lr & 7) << 3;             // read-side swizzle (halves)

    // ---- stage W1T [256][128] swizzled: thread t stages row t ----
    {
        const ushort* gw = W1T + t * 128;
        const int s = (t & 7) << 3;
        ushort* dstp = wbuf + t * 128;
        #pragma unroll
        for (int j = 0; j < 16; ++j) {
            short8 v = *reinterpret_cast<const short8*>(gw + j * 8);
            *reinterpret_cast<short8*>(dstp + ((j * 8) ^ s)) = v;
        }
    }

    // h_in row fragments for both groups (phase-1 B operand)
    short8 aA[4], aB[4];
    const ushort* apA = h_in + (size_t)arcA * IN_CH + lk * 8;
    const ushort* apB = h_in + (size_t)arcB * IN_CH + lk * 8;
    #pragma unroll
    for (int kk = 0; kk < 4; ++kk) {
        aA[kk] = *reinterpret_cast<const short8*>(apA + kk * 32);
        aB[kk] = *reinterpret_cast<const short8*>(apB + kk * 32);
    }

    __syncthreads();

    // ---- phase 1 (swapped): one weight frag -> two MFMAs ----
    int pkA[16][2], pkB[16][2];
    #pragma unroll
    for (int ct = 0; ct < 16; ++ct) {
        const ushort* bp = wbuf + (ct * 16 + lr) * 128;
        f32x4 accA = (f32x4){0.f, 0.f, 0.f, 0.f};
        f32x4 accB = (f32x4){0.f, 0.f, 0.f, 0.f};
        #pragma unroll
        for (int kk = 0; kk < 4; ++kk) {
            short8 wf = *reinterpret_cast<const short8*>(bp + ((lk * 8 + kk * 32) ^ sw));
            accA = __builtin_amdgcn_mfma_f32_16x16x32_bf16(wf, aA[kk], accA, 0, 0, 0);
            accB = __builtin_amdgcn_mfma_f32_16x16x32_bf16(wf, aB[kk], accB, 0, 0, 0);
        }
        const float4 bb = *reinterpret_cast<const float4*>(b1 + ct * 16 + lk * 4);
        pkA[ct][0] = (int)f2b(fmaxf(accA[0] + bb.x, 0.0f))
                   | ((int)f2b(fmaxf(accA[1] + bb.y, 0.0f)) << 16);
        pkA[ct][1] = (int)f2b(fmaxf(accA[2] + bb.z, 0.0f))
                   | ((int)f2b(fmaxf(accA[3] + bb.w, 0.0f)) << 16);
        pkB[ct][0] = (int)f2b(fmaxf(accB[0] + bb.x, 0.0f))
                   | ((int)f2b(fmaxf(accB[1] + bb.y, 0.0f)) << 16);
        pkB[ct][1] = (int)f2b(fmaxf(accB[2] + bb.z, 0.0f))
                   | ((int)f2b(fmaxf(accB[3] + bb.w, 0.0f)) << 16);
    }

    __syncthreads();   // all waves done reading W1 from wbuf

    // ---- stage W2T [128][256] swizzled: thread t stages half-row ----
    {
        const ushort* gw = W2T + t * 128;
        const int row = t >> 1;
        const int s = (row & 7) << 3;
        ushort* dstp = wbuf + row * 256;
        const int colbase = (t & 1) * 128;
        #pragma unroll
        for (int j = 0; j < 16; ++j) {
            short8 v = *reinterpret_cast<const short8*>(gw + j * 8);
            *reinterpret_cast<short8*>(dstp + ((colbase + j * 8) ^ s)) = v;
        }
    }

    // ---- in-register permutation x2: pk -> phase-2 A-frags ----
    short8 a2A[8], a2B[8];
    #pragma unroll
    for (int kk2 = 0; kk2 < 8; ++kk2) {
        const int Alo0 = pkA[2 * kk2][0],     Alo1 = pkA[2 * kk2][1];
        const int Ahi0 = pkA[2 * kk2 + 1][0], Ahi1 = pkA[2 * kk2 + 1][1];
        const int Blo0 = pkB[2 * kk2][0],     Blo1 = pkB[2 * kk2][1];
        const int Bhi0 = pkB[2 * kk2 + 1][0], Bhi1 = pkB[2 * kk2 + 1][1];
        union { int d[4]; short8 s8; } uA, uB;
        #pragma unroll
        for (int i = 0; i < 4; ++i) {
            const int srcLane = lr + 16 * ((2 * lk + (i >> 1)) & 3);
            const int vAlo = __shfl((i & 1) ? Alo1 : Alo0, srcLane, 64);
            const int vAhi = __shfl((i & 1) ? Ahi1 : Ahi0, srcLane, 64);
            const int vBlo = __shfl((i & 1) ? Blo1 : Blo0, srcLane, 64);
            const int vBhi = __shfl((i & 1) ? Bhi1 : Bhi0, srcLane, 64);
            uA.d[i] = (lk < 2) ? vAlo : vAhi;
            uB.d[i] = (lk < 2) ? vBlo : vBhi;
        }
        a2A[kk2] = uA.s8;
        a2B[kk2] = uB.s8;
    }

    __syncthreads();   // W2 staged

    // ---- phase 2: one weight frag -> two MFMAs ----
    f32x4 acc2A[8], acc2B[8];
    #pragma unroll
    for (int ct = 0; ct < 8; ++ct) {
        acc2A[ct] = (f32x4){0.f, 0.f, 0.f, 0.f};
        acc2B[ct] = (f32x4){0.f, 0.f, 0.f, 0.f};
    }

    #pragma unroll
    for (int ct = 0; ct < 8; ++ct) {
        const ushort* bp = wbuf + (ct * 16 + lr) * 256;
        #pragma unroll
        for (int kk = 0; kk < 8; ++kk) {
            short8 b = *reinterpret_cast<const short8*>(bp + ((lk * 8 + kk * 32) ^ sw));
            acc2A[ct] = __builtin_amdgcn_mfma_f32_16x16x32_bf16(a2A[kk], b, acc2A[ct], 0, 0, 0);
            acc2B[ct] = __builtin_amdgcn_mfma_f32_16x16x32_bf16(a2B[kk], b, acc2B[ct], 0, 0, 0);
        }
    }

    float bias[8];
    #pragma unroll
    for (int ct = 0; ct < 8; ++ct) bias[ct] = b2[ct * 16 + lr];

    // ---- epilogue (lsm) for both groups ----
    #pragma unroll
    for (int g = 0; g < 2; ++g) {
        const int orow0 = row0 + g * 16 + lk * 4;
        #pragma unroll
        for (int r = 0; r < 4; ++r) {
            float v[8];
            float m = -1e30f;
            #pragma unroll
            for (int ct = 0; ct < 8; ++ct) {
                const float av = g ? acc2B[ct][r] : acc2A[ct][r];
                v[ct] = fmaxf(av + bias[ct], 0.0f);
                m = fmaxf(m, v[ct]);
            }
            #pragma unroll
            for (int o = 1; o < 16; o <<= 1) m = fmaxf(m, __shfl_xor(m, o));
            float s = 0.0f;
            #pragma unroll
            for (int ct = 0; ct < 8; ++ct) s += __expf(v[ct] - m);
            #pragma unroll
            for (int o = 1; o < 16; o <<= 1) s += __shfl_xor(s, o);
            const float lse = m + __logf(s);
            const int orow = orow0 + r;
            if (orow < N_NODES) {
                #pragma unroll
                for (int ct = 0; ct < 8; ++ct)
                    out[(size_t)orow * OUT_CH + ct * 16 + lr] = v[ct] - lse;
            }
        }
    }
}

extern "C" void kernel_launch(void* const* d_in, const int* in_sizes, int n_in,
                              void* d_out, int out_size, void* d_ws, size_t ws_size,
                              hipStream_t stream) {
    const float* x    = (const float*)d_in[0];
    const int*   ei   = (const int*)d_in[1];
    const float* W1   = (const float*)d_in[2];
    const float* b1   = (const float*)d_in[3];
    const float* W2   = (const float*)d_in[4];
    const float* b2   = (const float*)d_in[5];
    const float* eps  = (const float*)d_in[6];
    float* out = (float*)d_out;

    // workspace layout
    ushort* xb   = (ushort*)d_ws;                          // 12.8M ushort
    ushort* h_in = xb + (size_t)N_NODES * IN_CH;           // 12.8M
    ushort* W1T  = h_in + (size_t)N_NODES * IN_CH;         // 32768
    ushort* W2T  = W1T + IN_CH * HID_CH;                   // 32768
    int* histT      = (int*)(W2T + HID_CH * OUT_CH);       // NBK*256
    int* blockBaseP = histT + NBK * BIN_BLOCKS;            // NBK*256
    int* bktTotal   = blockBaseP + NBK * BIN_BLOCKS;       // NBK
    int* begA       = bktTotal + NBK;                      // N_NODES
    int* endA       = begA + N_NODES;                      // N_NODES
    unsigned int* ebuf = (unsigned int*)(endA + N_NODES);  // NBK*BKT_CAP (12.8 MB)
    int* csr_src    = (int*)(ebuf + (size_t)NBK * BKT_CAP); // NBK*BKT_CAP (12.8 MB)

    const int* src = ei;
    const int* dst = ei + N_EDGES;

    prep_kernel<<<PREP_TOTAL + BIN_BLOCKS, 256, 0, stream>>>(
        x, W1, W2, dst, xb, W1T, W2T, histT);
    scanA_kernel<<<NBK, 256, 0, stream>>>(histT, blockBaseP, bktTotal);
    bin_kernel<<<BIN_BLOCKS, 256, 0, stream>>>(src, dst, blockBaseP, ebuf);
    group_kernel<<<NBK, 256, 0, stream>>>(ebuf, bktTotal, csr_src, begA, endA);
    gather_kernel<<<N_NODES / 8, 256, 0, stream>>>(xb, eps, begA, endA, csr_src, h_in);
    mlp_fused<<<(N_NODES + 127) / 128, 256, 0, stream>>>(h_in, W1T, W2T, b1, b2, out);
}